// Round 1
// baseline (709.348 us; speedup 1.0000x reference)
//
#include <hip/hip_runtime.h>
#include <math.h>

// Problem constants (fixed by setup_inputs): B=8192, T=1024, WS=5, H=6, IN=15, OUT=2
#define BATCH 8192
#define TLEN  1024
#define NSTEP 1019   // T - WS predictions per batch element
#define HID   6

__global__ __launch_bounds__(64) void MLP_or_nextstep_kernel(
    const float* __restrict__ traj,   // (B, T, 3)
    const float* __restrict__ W1,     // (6, 15)
    const float* __restrict__ b1,     // (6,)
    const float* __restrict__ W2,     // (2, 6)
    const float* __restrict__ b2,     // (2,)
    float* __restrict__ out)          // (B, 1019, 2)
{
    const int b = blockIdx.x * blockDim.x + threadIdx.x;
    const float* base = traj + (size_t)b * (TLEN * 3);
    float2* outb = (float2*)out + (size_t)b * NSTEP;

    // ---- load weights (uniform across lanes -> scalar regs) ----
    float w1[HID][15], b1v[HID], w2a[HID], w2b[HID], b2a, b2c;
#pragma unroll
    for (int i = 0; i < HID; ++i) {
#pragma unroll
        for (int j = 0; j < 15; ++j) w1[i][j] = W1[i * 15 + j];
        b1v[i] = b1[i];
        w2a[i] = W2[i];          // W2[0][i]
        w2b[i] = W2[HID + i];    // W2[1][i]
    }
    b2a = b2[0];
    b2c = b2[1];

    // fast accurate tanh: 1 - 2/(e^{2x}+1)
    auto mlp = [&](const float* __restrict__ x, float& ya, float& yb) {
        float h[HID];
#pragma unroll
        for (int i = 0; i < HID; ++i) {
            float acc = b1v[i];
#pragma unroll
            for (int j = 0; j < 15; ++j) acc = fmaf(w1[i][j], x[j], acc);
            float e = __expf(2.0f * acc);
            h[i] = 1.0f - 2.0f / (e + 1.0f);
        }
        float ta = b2a, tb = b2c;
#pragma unroll
        for (int i = 0; i < HID; ++i) {
            ta = fmaf(w2a[i], h[i], ta);
            tb = fmaf(w2b[i], h[i], tb);
        }
        ya = ta; yb = tb;
    };

    // ---- load warmup inputs: u[0..11], v[0..4], w[0..4] ----
    float uu[12], vv[5], wc[5];
#pragma unroll
    for (int i = 0; i < 12; ++i) uu[i] = base[i * 3];
#pragma unroll
    for (int i = 0; i < 5; ++i) { vv[i] = base[i * 3 + 1]; wc[i] = base[i * 3 + 2]; }

    float pa[5], pb[5];
    // warmup step 0: window = real rows t=0..4
    {
        float x[15] = {uu[0],uu[1],uu[2],uu[3],uu[4],
                       vv[0],vv[1],vv[2],vv[3],vv[4],
                       wc[0],wc[1],wc[2],wc[3],wc[4]};
        mlp(x, pa[0], pb[0]);
    }
    // warmup step 1: real t=1..4, pred row with u[5]
    {
        float x[15] = {uu[1],uu[2],uu[3],uu[4],uu[5],
                       vv[1],vv[2],vv[3],vv[4],pa[0],
                       wc[1],wc[2],wc[3],wc[4],pb[0]};
        mlp(x, pa[1], pb[1]);
    }
    // warmup step 2: real t=2..4, pred rows with u[6],u[7]
    {
        float x[15] = {uu[2],uu[3],uu[4],uu[6],uu[7],
                       vv[2],vv[3],vv[4],pa[0],pa[1],
                       wc[2],wc[3],wc[4],pb[0],pb[1]};
        mlp(x, pa[2], pb[2]);
    }
    // warmup step 3: real t=3..4, pred rows with u[7],u[8],u[9]
    {
        float x[15] = {uu[3],uu[4],uu[7],uu[8],uu[9],
                       vv[3],vv[4],pa[0],pa[1],pa[2],
                       wc[3],wc[4],pb[0],pb[1],pb[2]};
        mlp(x, pa[3], pb[3]);
    }
    // warmup step 4: real t=4, pred rows with u[8..11]
    {
        float x[15] = {uu[4],uu[8],uu[9],uu[10],uu[11],
                       vv[4],pa[0],pa[1],pa[2],pa[3],
                       wc[4],pb[0],pb[1],pb[2],pb[3]};
        mlp(x, pa[4], pb[4]);
    }
#pragma unroll
    for (int i = 0; i < 5; ++i) outb[i] = make_float2(pa[i], pb[i]);

    // ---- scan: t = 5 .. 1018 ----
    // u window with prefetch depth 8: uwin[i] = u[t+i] at loop entry (i<8)
    float uwin[8];
#pragma unroll
    for (int i = 0; i < 8; ++i) uwin[i] = base[(5 + i) * 3];   // u[5..12]

    float aw[5], bw[5];
#pragma unroll
    for (int i = 0; i < 5; ++i) { aw[i] = pa[i]; bw[i] = pb[i]; }

#pragma unroll 5
    for (int t = 5; t < NSTEP; ++t) {
        float x[15] = {uwin[0],uwin[1],uwin[2],uwin[3],uwin[4],
                       aw[0],aw[1],aw[2],aw[3],aw[4],
                       bw[0],bw[1],bw[2],bw[3],bw[4]};
        float ya, yb;
        mlp(x, ya, yb);
        outb[t] = make_float2(ya, yb);

        // shift windows
#pragma unroll
        for (int i = 0; i < 7; ++i) uwin[i] = uwin[i + 1];
#pragma unroll
        for (int i = 0; i < 4; ++i) { aw[i] = aw[i + 1]; bw[i] = bw[i + 1]; }
        aw[4] = ya; bw[4] = yb;

        int nidx = t + 8;                 // next u to prefetch: u[t+8]
        if (nidx > TLEN - 1) nidx = TLEN - 1;  // clamp (tail iterations)
        uwin[7] = base[nidx * 3];
    }
}

extern "C" void kernel_launch(void* const* d_in, const int* in_sizes, int n_in,
                              void* d_out, int out_size, void* d_ws, size_t ws_size,
                              hipStream_t stream) {
    const float* traj = (const float*)d_in[0];
    const float* W1   = (const float*)d_in[1];
    const float* b1   = (const float*)d_in[2];
    const float* W2   = (const float*)d_in[3];
    const float* b2   = (const float*)d_in[4];
    float* out = (float*)d_out;

    const int nthreads = BATCH;           // one thread per batch element
    const int block = 64;                 // 1 wave per block -> spread over CUs
    const int grid = nthreads / block;    // 128 blocks
    MLP_or_nextstep_kernel<<<grid, block, 0, stream>>>(traj, W1, b1, W2, b2, out);
}

// Round 2
// 457.648 us; speedup vs baseline: 1.5500x; 1.5500x over previous
//
#include <hip/hip_runtime.h>
#include <math.h>

// B=8192, T=1024, WS=5, H=6, IN=15, OUT=2
#define TLEN  1024
#define NSTEP 1019
#define HID   6
#define CHUNK 128
#define STAGE (CHUNK + 8)   // staged u rows per chunk (window + 8-deep prefetch)

__global__ __launch_bounds__(64) void MLP_or_nextstep_kernel(
    const float* __restrict__ traj,   // (B, T, 3)
    const float* __restrict__ W1,     // (6, 15)
    const float* __restrict__ b1,     // (6,)
    const float* __restrict__ W2,     // (2, 6)
    const float* __restrict__ b2,     // (2,)
    float* __restrict__ out)          // (B, 1019, 2)
{
    __shared__ float lds_u[STAGE][64];   // [time-row][lane] : 34 KB

    const int lane = threadIdx.x;
    const int b = blockIdx.x * 64 + lane;
    const float* __restrict__ base = traj + (size_t)b * (TLEN * 3);
    float2* outb = (float2*)out + (size_t)b * NSTEP;

    // ---- weights (wave-uniform -> SGPRs). Layer-1 pre-doubled: tanh(z) = 1 - 2/(e^{2z}+1)
    float w1[HID][15], b1v[HID], w2a[HID], w2b[HID], b2a, b2c;
#pragma unroll
    for (int i = 0; i < HID; ++i) {
#pragma unroll
        for (int j = 0; j < 15; ++j) w1[i][j] = 2.0f * W1[i * 15 + j];
        b1v[i] = 2.0f * b1[i];
        w2a[i] = W2[i];          // W2[0][i]
        w2b[i] = W2[HID + i];    // W2[1][i]
    }
    b2a = b2[0];
    b2c = b2[1];

    auto mlp = [&](const float* __restrict__ x, float& ya, float& yb) {
        float h[HID];
#pragma unroll
        for (int i = 0; i < HID; ++i) {
            float z = b1v[i];                       // already 2*b1
#pragma unroll
            for (int j = 0; j < 15; ++j) z = fmaf(w1[i][j], x[j], z);   // z = 2*preact
            float e = __expf(z);                    // e^{2*preact}
            float r = __builtin_amdgcn_rcpf(e + 1.0f);
            h[i] = fmaf(-2.0f, r, 1.0f);            // tanh(preact)
        }
        // layer 2, shallow tree
        float ta = fmaf(w2a[0], h[0], w2a[1] * h[1]);
        float tb = fmaf(w2b[0], h[0], w2b[1] * h[1]);
        ta = fmaf(w2a[2], h[2], ta);  tb = fmaf(w2b[2], h[2], tb);
        float ua = fmaf(w2a[3], h[3], w2a[4] * h[4]);
        float ub = fmaf(w2b[3], h[3], w2b[4] * h[4]);
        ua = fmaf(w2a[5], h[5], ua);  ub = fmaf(w2b[5], h[5], ub);
        ya = (ta + ua) + b2a;
        yb = (tb + ub) + b2c;
    };

    // ---- warmup inputs: u[0..11], v[0..4], w[0..4] (one-time, latency irrelevant)
    float uu[12], vv[5], wc[5];
#pragma unroll
    for (int i = 0; i < 12; ++i) uu[i] = base[i * 3];
#pragma unroll
    for (int i = 0; i < 5; ++i) { vv[i] = base[i * 3 + 1]; wc[i] = base[i * 3 + 2]; }

    float pa[5], pb[5];
    {
        float x[15] = {uu[0],uu[1],uu[2],uu[3],uu[4],
                       vv[0],vv[1],vv[2],vv[3],vv[4],
                       wc[0],wc[1],wc[2],wc[3],wc[4]};
        mlp(x, pa[0], pb[0]);
    }
    {
        float x[15] = {uu[1],uu[2],uu[3],uu[4],uu[5],
                       vv[1],vv[2],vv[3],vv[4],pa[0],
                       wc[1],wc[2],wc[3],wc[4],pb[0]};
        mlp(x, pa[1], pb[1]);
    }
    {
        float x[15] = {uu[2],uu[3],uu[4],uu[6],uu[7],
                       vv[2],vv[3],vv[4],pa[0],pa[1],
                       wc[2],wc[3],wc[4],pb[0],pb[1]};
        mlp(x, pa[2], pb[2]);
    }
    {
        float x[15] = {uu[3],uu[4],uu[7],uu[8],uu[9],
                       vv[3],vv[4],pa[0],pa[1],pa[2],
                       wc[3],wc[4],pb[0],pb[1],pb[2]};
        mlp(x, pa[3], pb[3]);
    }
    {
        float x[15] = {uu[4],uu[8],uu[9],uu[10],uu[11],
                       vv[4],pa[0],pa[1],pa[2],pa[3],
                       wc[4],pb[0],pb[1],pb[2],pb[3]};
        mlp(x, pa[4], pb[4]);
    }
#pragma unroll
    for (int i = 0; i < 5; ++i) outb[i] = make_float2(pa[i], pb[i]);

    // ---- scan t = 5 .. 1018, chunked so the hot loop has ZERO global loads
    float aw[5], bw[5];
#pragma unroll
    for (int i = 0; i < 5; ++i) { aw[i] = pa[i]; bw[i] = pb[i]; }

    for (int t0 = 5; t0 < NSTEP; t0 += CHUNK) {
        int len = NSTEP - t0; if (len > CHUNK) len = CHUNK;

        // stage u[t0 .. t0+STAGE-1] (clamped) into LDS, async, one drain.
        // lds dest = uniform base + lane*4  ->  lds_u[r][lane]; gaddr per-lane (own b).
        for (int r = 0; r < STAGE; ++r) {
            int ti = t0 + r; if (ti > TLEN - 1) ti = TLEN - 1;
            const float* gp = base + (size_t)ti * 3;
            __builtin_amdgcn_global_load_lds(
                (const __attribute__((address_space(1))) void*)gp,
                (__attribute__((address_space(3))) void*)&lds_u[r][0],
                4, 0, 0);
        }
        __syncthreads();   // single vmcnt(0) drain per chunk; LDS now valid

        float uwin[8];
#pragma unroll
        for (int i = 0; i < 8; ++i) uwin[i] = lds_u[i][lane];   // u[t0 .. t0+7]

#pragma unroll 2
        for (int c = 0; c < len; ++c) {
            float x[15] = {uwin[0],uwin[1],uwin[2],uwin[3],uwin[4],
                           aw[0],aw[1],aw[2],aw[3],aw[4],
                           bw[0],bw[1],bw[2],bw[3],bw[4]};
            float ya, yb;
            mlp(x, ya, yb);
            outb[t0 + c] = make_float2(ya, yb);   // fire-and-forget; nothing waits on it

            // shift windows (register-renamed under unroll)
#pragma unroll
            for (int i = 0; i < 7; ++i) uwin[i] = uwin[i + 1];
#pragma unroll
            for (int i = 0; i < 4; ++i) { aw[i] = aw[i + 1]; bw[i] = bw[i + 1]; }
            aw[4] = ya; bw[4] = yb;

            uwin[7] = lds_u[c + 8][lane];         // ds_read, prefetch depth 8 steps
        }
        __syncthreads();   // keep staging of next chunk behind all reads (1 wave: cheap)
    }
}

extern "C" void kernel_launch(void* const* d_in, const int* in_sizes, int n_in,
                              void* d_out, int out_size, void* d_ws, size_t ws_size,
                              hipStream_t stream) {
    const float* traj = (const float*)d_in[0];
    const float* W1   = (const float*)d_in[1];
    const float* b1   = (const float*)d_in[2];
    const float* W2   = (const float*)d_in[3];
    const float* b2   = (const float*)d_in[4];
    float* out = (float*)d_out;

    const int grid = 8192 / 64;   // one thread per batch element, 1 wave per block
    MLP_or_nextstep_kernel<<<grid, 64, 0, stream>>>(traj, W1, b1, W2, b2, out);
}

// Round 3
// 283.985 us; speedup vs baseline: 2.4978x; 1.6115x over previous
//
#include <hip/hip_runtime.h>
#include <math.h>

// B=8192, T=1024, WS=5, H=6, IN=15, OUT=2
#define TLEN  1024
#define NSTEP 1019
#define CHUNK 128
#define STAGE (CHUNK + 8)   // staged u rows per chunk (window + 8-deep prefetch)

// DPP-based sum over each consecutive 8-lane group (result in all 8 lanes).
// rounds: quad_perm xor1 (0xB1), quad_perm xor2 (0x4E), row_half_mirror (0x141 = xor7)
template <int CTRL>
__device__ __forceinline__ float dpp_add(float v) {
    union { int i; float f; } in, out;
    in.f = v;
    out.i = __builtin_amdgcn_update_dpp(0, in.i, CTRL, 0xF, 0xF, false);
    return v + out.f;
}
__device__ __forceinline__ float sum8(float v) {
    v = dpp_add<0xB1>(v);
    v = dpp_add<0x4E>(v);
    v = dpp_add<0x141>(v);
    return v;
}

__global__ __launch_bounds__(64) void MLP_or_nextstep_kernel(
    const float* __restrict__ traj,   // (B, T, 3)
    const float* __restrict__ W1,     // (6, 15)
    const float* __restrict__ b1,     // (6,)
    const float* __restrict__ W2,     // (2, 6)
    const float* __restrict__ b2,     // (2,)
    float* __restrict__ out)          // (B, 1019, 2)
{
    __shared__ float lds_u[STAGE][8];   // [time-row][element] : 4352 B

    const int lane = threadIdx.x;
    const int g    = lane >> 3;         // element slot within wave (compute mapping)
    const int n    = lane & 7;          // neuron id (0..5 real, 6..7 dummy)
    const int bstart = blockIdx.x * 8;
    const int b = bstart + g;           // this lane's batch element

    const float* __restrict__ base = traj + (size_t)b * (TLEN * 3);
    float2* outb = (float2*)out + (size_t)b * NSTEP;
    const bool is_store_lane = (n == 0);

    // ---- per-lane weights: row of layer-1 for neuron n (pre-doubled: tanh(z)=1-2/(e^{2z}+1))
    const int nr = (n < 6) ? n : 5;     // dummy lanes compute neuron 5, weighted 0 in layer 2
    float w1row[15], b1r;
#pragma unroll
    for (int j = 0; j < 15; ++j) w1row[j] = 2.0f * W1[nr * 15 + j];
    b1r = 2.0f * b1[nr];
    const float w2a_l = (n < 6) ? W2[n]     : 0.0f;   // W2[0][n]
    const float w2b_l = (n < 6) ? W2[6 + n] : 0.0f;   // W2[1][n]
    const float b2a = b2[0], b2c = b2[1];

    // lane-parallel MLP step: x[15] identical across the 8 lanes of a group
    auto mlp = [&](const float* __restrict__ x, float& ya, float& yb) {
        // three parallel 5-deep FMA chains
        float z0 = w1row[0] * x[0];
        float z1 = w1row[5] * x[5];
        float z2 = fmaf(w1row[10], x[10], b1r);
#pragma unroll
        for (int j = 1; j < 5; ++j) {
            z0 = fmaf(w1row[j],      x[j],      z0);
            z1 = fmaf(w1row[5 + j],  x[5 + j],  z1);
            z2 = fmaf(w1row[10 + j], x[10 + j], z2);
        }
        float z = (z0 + z1) + z2;                       // = 2 * preact
        float e = __expf(z);
        float h = fmaf(-2.0f, __builtin_amdgcn_rcpf(e + 1.0f), 1.0f);  // tanh(preact)
        float sa = sum8(h * w2a_l);
        float sb = sum8(h * w2b_l);
        ya = sa + b2a;
        yb = sb + b2c;
    };

    // ---- warmup inputs (one-time, latency-irrelevant; 8 lanes/group read same addrs)
    float uu[12], vv[5], wc[5];
#pragma unroll
    for (int i = 0; i < 12; ++i) uu[i] = base[i * 3];
#pragma unroll
    for (int i = 0; i < 5; ++i) { vv[i] = base[i * 3 + 1]; wc[i] = base[i * 3 + 2]; }

    float pa[5], pb[5];
    {
        float x[15] = {uu[0],uu[1],uu[2],uu[3],uu[4],
                       vv[0],vv[1],vv[2],vv[3],vv[4],
                       wc[0],wc[1],wc[2],wc[3],wc[4]};
        mlp(x, pa[0], pb[0]);
    }
    {
        float x[15] = {uu[1],uu[2],uu[3],uu[4],uu[5],
                       vv[1],vv[2],vv[3],vv[4],pa[0],
                       wc[1],wc[2],wc[3],wc[4],pb[0]};
        mlp(x, pa[1], pb[1]);
    }
    {
        float x[15] = {uu[2],uu[3],uu[4],uu[6],uu[7],
                       vv[2],vv[3],vv[4],pa[0],pa[1],
                       wc[2],wc[3],wc[4],pb[0],pb[1]};
        mlp(x, pa[2], pb[2]);
    }
    {
        float x[15] = {uu[3],uu[4],uu[7],uu[8],uu[9],
                       vv[3],vv[4],pa[0],pa[1],pa[2],
                       wc[3],wc[4],pb[0],pb[1],pb[2]};
        mlp(x, pa[3], pb[3]);
    }
    {
        float x[15] = {uu[4],uu[8],uu[9],uu[10],uu[11],
                       vv[4],pa[0],pa[1],pa[2],pa[3],
                       wc[4],pb[0],pb[1],pb[2],pb[3]};
        mlp(x, pa[4], pb[4]);
    }
    if (is_store_lane) {
#pragma unroll
        for (int i = 0; i < 5; ++i) outb[i] = make_float2(pa[i], pb[i]);
    }

    // ---- scan t = 5 .. 1018, chunked; hot loop has zero global loads
    float aw[5], bw[5];
#pragma unroll
    for (int i = 0; i < 5; ++i) { aw[i] = pa[i]; bw[i] = pb[i]; }

    // staging lane mapping (differs from compute mapping on purpose):
    // lane i writes LDS word (base + 4*i) = lds_u[r0 + (i>>3)][i&7]
    // -> lane i must load u of element (i&7) at row r0 + (i>>3)
    const int s_elem = lane & 7;
    const int s_row  = lane >> 3;
    const float* __restrict__ sbase = traj + (size_t)(bstart + s_elem) * (TLEN * 3);

    for (int t0 = 5; t0 < NSTEP; t0 += CHUNK) {
        int len = NSTEP - t0; if (len > CHUNK) len = CHUNK;

        // stage u[t0 .. t0+STAGE-1] (clamped): 17 async load_lds instrs, one drain
        for (int r0 = 0; r0 < STAGE; r0 += 8) {
            int ti = t0 + r0 + s_row;
            if (ti > TLEN - 1) ti = TLEN - 1;     // tail clamp (never consumed in x)
            const float* gp = sbase + (size_t)ti * 3;
            __builtin_amdgcn_global_load_lds(
                (const __attribute__((address_space(1))) void*)gp,
                (__attribute__((address_space(3))) void*)&lds_u[r0][0],
                4, 0, 0);
        }
        __syncthreads();

        float uwin[8];
#pragma unroll
        for (int i = 0; i < 8; ++i) uwin[i] = lds_u[i][g];   // u[t0 .. t0+7]

#pragma unroll 2
        for (int c = 0; c < len; ++c) {
            float unext = lds_u[c + 8][g];   // issue early; consumed ~3 iters later

            float x[15] = {uwin[0],uwin[1],uwin[2],uwin[3],uwin[4],
                           aw[0],aw[1],aw[2],aw[3],aw[4],
                           bw[0],bw[1],bw[2],bw[3],bw[4]};
            float ya, yb;
            mlp(x, ya, yb);
            if (is_store_lane) outb[t0 + c] = make_float2(ya, yb);  // fire-and-forget

#pragma unroll
            for (int i = 0; i < 7; ++i) uwin[i] = uwin[i + 1];
#pragma unroll
            for (int i = 0; i < 4; ++i) { aw[i] = aw[i + 1]; bw[i] = bw[i + 1]; }
            aw[4] = ya; bw[4] = yb;
            uwin[7] = unext;
        }
        __syncthreads();   // staging of next chunk must stay behind reads
    }
}

extern "C" void kernel_launch(void* const* d_in, const int* in_sizes, int n_in,
                              void* d_out, int out_size, void* d_ws, size_t ws_size,
                              hipStream_t stream) {
    const float* traj = (const float*)d_in[0];
    const float* W1   = (const float*)d_in[1];
    const float* b1   = (const float*)d_in[2];
    const float* W2   = (const float*)d_in[3];
    const float* b2   = (const float*)d_in[4];
    float* out = (float*)d_out;

    // 8 lanes per batch element, 8 elements per wave -> 1024 blocks of 1 wave:
    // one wave on every SIMD of the 256-CU chip.
    const int grid = 8192 / 8;
    MLP_or_nextstep_kernel<<<grid, 64, 0, stream>>>(traj, W1, b1, W2, b2, out);
}

// Round 4
// 265.335 us; speedup vs baseline: 2.6734x; 1.0703x over previous
//
#include <hip/hip_runtime.h>
#include <math.h>

// B=8192, T=1024, WS=5, H=6, IN=15, OUT=2
#define TLEN  1024
#define NSTEP 1019

// DPP sum over each consecutive 8-lane group (result in all 8 lanes).
template <int CTRL>
__device__ __forceinline__ float dpp_add(float v) {
    union { int i; float f; } in, out;
    in.f = v;
    out.i = __builtin_amdgcn_update_dpp(0, in.i, CTRL, 0xF, 0xF, false);
    return v + out.f;
}
__device__ __forceinline__ float sum8(float v) {
    v = dpp_add<0xB1>(v);    // quad_perm xor1
    v = dpp_add<0x4E>(v);    // quad_perm xor2
    v = dpp_add<0x141>(v);   // row_half_mirror = xor4
    return v;
}

__device__ __forceinline__ float fast_exp2(float z) {
#if __has_builtin(__builtin_amdgcn_exp2f)
    return __builtin_amdgcn_exp2f(z);
#else
    return exp2f(z);
#endif
}

__global__ __launch_bounds__(64) void MLP_or_nextstep_kernel(
    const float* __restrict__ traj,   // (B, T, 3)
    const float* __restrict__ W1,     // (6, 15)
    const float* __restrict__ b1,     // (6,)
    const float* __restrict__ W2,     // (2, 6)
    const float* __restrict__ b2,     // (2,)
    float* __restrict__ out)          // (B, 1019, 2)
{
    __shared__ float lds_u[TLEN][8];  // 32 KB: u for the block's 8 elements, all T

    const int lane = threadIdx.x;
    const int g    = lane >> 3;        // element slot (compute mapping)
    const int n    = lane & 7;         // neuron id (0..5 real; 6,7 carry biases)
    const int bstart = blockIdx.x * 8;
    const int b = bstart + g;

    const float* __restrict__ base = traj + (size_t)b * (TLEN * 3);
    float2* outb = (float2*)out + (size_t)b * NSTEP;
    const bool is_store_lane = (n == 0);

    // ---- stage ALL u rows: lane i -> elem (i&7), row 8j+(i>>3); dest word 64j+i ----
    {
        const int s_elem = lane & 7;
        const int s_row  = lane >> 3;
        const float* __restrict__ sbase = traj + (size_t)(bstart + s_elem) * (TLEN * 3);
        for (int j = 0; j < TLEN / 8; ++j) {
            const float* gp = sbase + (size_t)(8 * j + s_row) * 3;
            __builtin_amdgcn_global_load_lds(
                (const __attribute__((address_space(1))) void*)gp,
                (__attribute__((address_space(3))) void*)&lds_u[8 * j][0],
                4, 0, 0);
        }
    }

    // ---- per-lane weights, fully folded ----
    // z = (2*log2e)*preact ; tanh(preact) = 1 - 2/(2^z + 1) = 1 - 2*r
    // p = w2a*tanh + bias  = fmaf(-2*w2a, r, w2a + bias)
    const float KK = 2.8853900817779268f;   // 2*log2(e)
    const int nr = (n < 6) ? n : 5;
    float w1row[15], b1r;
#pragma unroll
    for (int j = 0; j < 15; ++j) w1row[j] = KK * W1[nr * 15 + j];
    b1r = KK * b1[nr];
    const float w2a_l = (n < 6) ? W2[n]     : 0.0f;
    const float w2b_l = (n < 6) ? W2[6 + n] : 0.0f;
    const float bias_a = (n == 6) ? b2[0] : 0.0f;
    const float bias_b = (n == 7) ? b2[1] : 0.0f;
    const float c1a = -2.0f * w2a_l, c0a = w2a_l + bias_a;
    const float c1b = -2.0f * w2b_l, c0b = w2b_l + bias_b;

    auto mlp = [&](const float* __restrict__ x, float& ya, float& yb) {
        float z0 = w1row[0] * x[0];
        float z1 = w1row[5] * x[5];
        float z2 = fmaf(w1row[10], x[10], b1r);
#pragma unroll
        for (int j = 1; j < 5; ++j) {
            z0 = fmaf(w1row[j],      x[j],      z0);
            z1 = fmaf(w1row[5 + j],  x[5 + j],  z1);
            z2 = fmaf(w1row[10 + j], x[10 + j], z2);
        }
        float z = (z0 + z1) + z2;
        float r = __builtin_amdgcn_rcpf(fast_exp2(z) + 1.0f);
        ya = sum8(fmaf(c1a, r, c0a));
        yb = sum8(fmaf(c1b, r, c0b));
    };

    // ---- warmup (one-time; latency-irrelevant) ----
    float uu[12], vv[5], wc[5];
#pragma unroll
    for (int i = 0; i < 12; ++i) uu[i] = base[i * 3];
#pragma unroll
    for (int i = 0; i < 5; ++i) { vv[i] = base[i * 3 + 1]; wc[i] = base[i * 3 + 2]; }

    float pa[5], pb[5];
    {
        float x[15] = {uu[0],uu[1],uu[2],uu[3],uu[4],
                       vv[0],vv[1],vv[2],vv[3],vv[4],
                       wc[0],wc[1],wc[2],wc[3],wc[4]};
        mlp(x, pa[0], pb[0]);
    }
    {
        float x[15] = {uu[1],uu[2],uu[3],uu[4],uu[5],
                       vv[1],vv[2],vv[3],vv[4],pa[0],
                       wc[1],wc[2],wc[3],wc[4],pb[0]};
        mlp(x, pa[1], pb[1]);
    }
    {
        float x[15] = {uu[2],uu[3],uu[4],uu[6],uu[7],
                       vv[2],vv[3],vv[4],pa[0],pa[1],
                       wc[2],wc[3],wc[4],pb[0],pb[1]};
        mlp(x, pa[2], pb[2]);
    }
    {
        float x[15] = {uu[3],uu[4],uu[7],uu[8],uu[9],
                       vv[3],vv[4],pa[0],pa[1],pa[2],
                       wc[3],wc[4],pb[0],pb[1],pb[2]};
        mlp(x, pa[3], pb[3]);
    }
    {
        float x[15] = {uu[4],uu[8],uu[9],uu[10],uu[11],
                       vv[4],pa[0],pa[1],pa[2],pa[3],
                       wc[4],pb[0],pb[1],pb[2],pb[3]};
        mlp(x, pa[4], pb[4]);
    }
    if (is_store_lane) {
#pragma unroll
        for (int i = 0; i < 5; ++i) outb[i] = make_float2(pa[i], pb[i]);
    }

    __syncthreads();   // staging drain (vmcnt(0) + barrier), once

    // ---- scan t = 5..1018 in 5-step groups; circular aw/bw fully renamed ----
    // slot k holds pred for time t0-5+k at group entry
    float aw[5], bw[5];
#pragma unroll
    for (int i = 0; i < 5; ++i) { aw[i] = pa[i]; bw[i] = pb[i]; }

    const float* up = &lds_u[5][g];    // u[t0 + i] = up[8*i]
    float2* op = outb + 5;

#define STEP_BODY(s, UN)                                                     \
    {                                                                        \
        float z0 = w1row[0] * UN[s];                                         \
        float z1 = w1row[5] * aw[(s) % 5];                                   \
        float z2 = fmaf(w1row[10], bw[(s) % 5], b1r);                        \
        z0 = fmaf(w1row[1], UN[s + 1], z0);                                  \
        z1 = fmaf(w1row[6], aw[(s + 1) % 5], z1);                            \
        z2 = fmaf(w1row[11], bw[(s + 1) % 5], z2);                           \
        z0 = fmaf(w1row[2], UN[s + 2], z0);                                  \
        z1 = fmaf(w1row[7], aw[(s + 2) % 5], z1);                            \
        z2 = fmaf(w1row[12], bw[(s + 2) % 5], z2);                           \
        z0 = fmaf(w1row[3], UN[s + 3], z0);                                  \
        z1 = fmaf(w1row[8], aw[(s + 3) % 5], z1);                            \
        z2 = fmaf(w1row[13], bw[(s + 3) % 5], z2);                           \
        z0 = fmaf(w1row[4], UN[s + 4], z0);                                  \
        z1 = fmaf(w1row[9], aw[(s + 4) % 5], z1);                            \
        z2 = fmaf(w1row[14], bw[(s + 4) % 5], z2);                           \
        float z = (z0 + z1) + z2;                                            \
        float r = __builtin_amdgcn_rcpf(fast_exp2(z) + 1.0f);                \
        float ya = sum8(fmaf(c1a, r, c0a));                                  \
        float yb = sum8(fmaf(c1b, r, c0b));                                  \
        if (is_store_lane) op[s] = make_float2(ya, yb);                      \
        aw[(s) % 5] = ya; bw[(s) % 5] = yb;                                  \
    }

    for (int grp = 0; grp < 202; ++grp) {      // t0 = 5 + 5*grp, covers t=5..1014
        float un[9];
#pragma unroll
        for (int i = 0; i < 9; ++i) un[i] = up[8 * i];
        STEP_BODY(0, un)
        STEP_BODY(1, un)
        STEP_BODY(2, un)
        STEP_BODY(3, un)
        STEP_BODY(4, un)
        up += 40;          // +5 rows
        op += 5;
    }
    // tail: t = 1015..1018 (4 steps); reads u[1015..1022]
    {
        float un[8];
#pragma unroll
        for (int i = 0; i < 8; ++i) un[i] = up[8 * i];
        STEP_BODY(0, un)
        STEP_BODY(1, un)
        STEP_BODY(2, un)
        STEP_BODY(3, un)
    }
#undef STEP_BODY
}

extern "C" void kernel_launch(void* const* d_in, const int* in_sizes, int n_in,
                              void* d_out, int out_size, void* d_ws, size_t ws_size,
                              hipStream_t stream) {
    const float* traj = (const float*)d_in[0];
    const float* W1   = (const float*)d_in[1];
    const float* b1   = (const float*)d_in[2];
    const float* W2   = (const float*)d_in[3];
    const float* b2   = (const float*)d_in[4];
    float* out = (float*)d_out;

    // 8 lanes/element, 8 elements/wave -> 1024 single-wave blocks = 1 wave/SIMD chip-wide
    const int grid = 8192 / 8;
    MLP_or_nextstep_kernel<<<grid, 64, 0, stream>>>(traj, W1, b1, W2, b2, out);
}

// Round 5
// 246.303 us; speedup vs baseline: 2.8800x; 1.0773x over previous
//
#include <hip/hip_runtime.h>
#include <math.h>

// B=8192, T=1024, WS=5, H=6, IN=15, OUT=2
#define TLEN  1024
#define NSTEP 1019

// DPP sum over each consecutive 8-lane group (result in all 8 lanes).
template <int CTRL>
__device__ __forceinline__ float dpp_add(float v) {
    union { int i; float f; } in, out;
    in.f = v;
    out.i = __builtin_amdgcn_update_dpp(0, in.i, CTRL, 0xF, 0xF, false);
    return v + out.f;
}
__device__ __forceinline__ float sum8(float v) {
    v = dpp_add<0xB1>(v);    // quad_perm xor1
    v = dpp_add<0x4E>(v);    // quad_perm xor2
    v = dpp_add<0x141>(v);   // row_half_mirror = xor4
    return v;
}

__device__ __forceinline__ float fast_exp2(float z) {
#if __has_builtin(__builtin_amdgcn_exp2f)
    return __builtin_amdgcn_exp2f(z);
#else
    return exp2f(z);
#endif
}

__global__ __launch_bounds__(64) void MLP_or_nextstep_kernel(
    const float* __restrict__ traj,   // (B, T, 3)
    const float* __restrict__ W1,     // (6, 15)
    const float* __restrict__ b1,     // (6,)
    const float* __restrict__ W2,     // (2, 6)
    const float* __restrict__ b2,     // (2,)
    float* __restrict__ out)          // (B, 1019, 2)
{
    __shared__ float lds_u[TLEN][8];  // 32 KB: u for the block's 8 elements, all T

    const int lane = threadIdx.x;
    const int g    = lane >> 3;        // element slot (compute mapping)
    const int n    = lane & 7;         // neuron id (0..5 real; 6,7 carry biases)
    const int bstart = blockIdx.x * 8;
    const int b = bstart + g;

    const float* __restrict__ base = traj + (size_t)b * (TLEN * 3);
    float2* outb = (float2*)out + (size_t)b * NSTEP;
    const bool is_store_lane = (n == 0);

    // ---- stage ALL u rows: lane i -> elem (i&7), row 8j+(i>>3); dest word 64j+i ----
    {
        const int s_elem = lane & 7;
        const int s_row  = lane >> 3;
        const float* __restrict__ sbase = traj + (size_t)(bstart + s_elem) * (TLEN * 3);
        for (int j = 0; j < TLEN / 8; ++j) {
            const float* gp = sbase + (size_t)(8 * j + s_row) * 3;
            __builtin_amdgcn_global_load_lds(
                (const __attribute__((address_space(1))) void*)gp,
                (__attribute__((address_space(3))) void*)&lds_u[8 * j][0],
                4, 0, 0);
        }
    }

    // ---- per-lane weights, fully folded ----
    // z = (2*log2e)*preact ; tanh(preact) = 1 - 2/(2^z + 1) = 1 - 2*r
    // p = w2*tanh + bias   = fmaf(-2*w2, r, w2 + bias)
    const float KK = 2.8853900817779268f;   // 2*log2(e)
    const int nr = (n < 6) ? n : 5;
    float w1row[15], b1r;
#pragma unroll
    for (int j = 0; j < 15; ++j) w1row[j] = KK * W1[nr * 15 + j];
    b1r = KK * b1[nr];
    const float w2a_l = (n < 6) ? W2[n]     : 0.0f;
    const float w2b_l = (n < 6) ? W2[6 + n] : 0.0f;
    const float bias_a = (n == 6) ? b2[0] : 0.0f;
    const float bias_b = (n == 7) ? b2[1] : 0.0f;
    const float c1a = -2.0f * w2a_l, c0a = w2a_l + bias_a;
    const float c1b = -2.0f * w2b_l, c0b = w2b_l + bias_b;

    auto mlp = [&](const float* __restrict__ x, float& ya, float& yb) {
        float z0 = w1row[0] * x[0];
        float z1 = w1row[5] * x[5];
        float z2 = fmaf(w1row[10], x[10], b1r);
#pragma unroll
        for (int j = 1; j < 5; ++j) {
            z0 = fmaf(w1row[j],      x[j],      z0);
            z1 = fmaf(w1row[5 + j],  x[5 + j],  z1);
            z2 = fmaf(w1row[10 + j], x[10 + j], z2);
        }
        float z = (z0 + z1) + z2;
        float r = __builtin_amdgcn_rcpf(fast_exp2(z) + 1.0f);
        ya = sum8(fmaf(c1a, r, c0a));
        yb = sum8(fmaf(c1b, r, c0b));
    };

    // ---- warmup (one-time; latency-irrelevant) ----
    float uu[12], vv[5], wc[5];
#pragma unroll
    for (int i = 0; i < 12; ++i) uu[i] = base[i * 3];
#pragma unroll
    for (int i = 0; i < 5; ++i) { vv[i] = base[i * 3 + 1]; wc[i] = base[i * 3 + 2]; }

    float pa[5], pb[5];
    {
        float x[15] = {uu[0],uu[1],uu[2],uu[3],uu[4],
                       vv[0],vv[1],vv[2],vv[3],vv[4],
                       wc[0],wc[1],wc[2],wc[3],wc[4]};
        mlp(x, pa[0], pb[0]);
    }
    {
        float x[15] = {uu[1],uu[2],uu[3],uu[4],uu[5],
                       vv[1],vv[2],vv[3],vv[4],pa[0],
                       wc[1],wc[2],wc[3],wc[4],pb[0]};
        mlp(x, pa[1], pb[1]);
    }
    {
        float x[15] = {uu[2],uu[3],uu[4],uu[6],uu[7],
                       vv[2],vv[3],vv[4],pa[0],pa[1],
                       wc[2],wc[3],wc[4],pb[0],pb[1]};
        mlp(x, pa[2], pb[2]);
    }
    {
        float x[15] = {uu[3],uu[4],uu[7],uu[8],uu[9],
                       vv[3],vv[4],pa[0],pa[1],pa[2],
                       wc[3],wc[4],pb[0],pb[1],pb[2]};
        mlp(x, pa[3], pb[3]);
    }
    {
        float x[15] = {uu[4],uu[8],uu[9],uu[10],uu[11],
                       vv[4],pa[0],pa[1],pa[2],pa[3],
                       wc[4],pb[0],pb[1],pb[2],pb[3]};
        mlp(x, pa[4], pb[4]);
    }
    if (is_store_lane) {
#pragma unroll
        for (int i = 0; i < 5; ++i) outb[i] = make_float2(pa[i], pb[i]);
    }

    __syncthreads();   // staging drain, once

    // ---- scan t = 5..1018 ----
    float aw[5], bw[5];
#pragma unroll
    for (int i = 0; i < 5; ++i) { aw[i] = pa[i]; bw[i] = pb[i]; }

    const float* up  = &lds_u[5][g];   // group base: u[t0+i] = up[8*i]
    const float* upn;
    float2* sp = outb + n + 5;         // lane n stores step-slot n of each 8-block
    float unA[9], unB[9];

    // preload first group (t0=5) into A
#pragma unroll
    for (int i = 0; i < 9; ++i) unA[i] = up[8 * i];
    upn = up + 40;                     // next group to load: t0=10

#define LOADN(BUF)                                                           \
    {                                                                        \
        _Pragma("unroll")                                                    \
        for (int i = 0; i < 9; ++i) BUF[i] = upn[8 * i];                     \
        upn += 40;                                                           \
    }

#define STEP(S, UN, J, M)                                                    \
    {                                                                        \
        float z0 = w1row[0] * UN[S];                                         \
        float z1 = w1row[5] * aw[(S) % 5];                                   \
        float z2 = fmaf(w1row[10], bw[(S) % 5], b1r);                        \
        z0 = fmaf(w1row[1], UN[(S) + 1], z0);                                \
        z1 = fmaf(w1row[6], aw[((S) + 1) % 5], z1);                          \
        z2 = fmaf(w1row[11], bw[((S) + 1) % 5], z2);                         \
        z0 = fmaf(w1row[2], UN[(S) + 2], z0);                                \
        z1 = fmaf(w1row[7], aw[((S) + 2) % 5], z1);                          \
        z2 = fmaf(w1row[12], bw[((S) + 2) % 5], z2);                         \
        z0 = fmaf(w1row[3], UN[(S) + 3], z0);                                \
        z1 = fmaf(w1row[8], aw[((S) + 3) % 5], z1);                          \
        z2 = fmaf(w1row[13], bw[((S) + 3) % 5], z2);                         \
        z0 = fmaf(w1row[4], UN[(S) + 4], z0);                                \
        z1 = fmaf(w1row[9], aw[((S) + 4) % 5], z1);                          \
        z2 = fmaf(w1row[14], bw[((S) + 4) % 5], z2);                         \
        float z = (z0 + z1) + z2;                                            \
        float r = __builtin_amdgcn_rcpf(fast_exp2(z) + 1.0f);                \
        float ya = sum8(fmaf(c1a, r, c0a));                                  \
        float yb = sum8(fmaf(c1b, r, c0b));                                  \
        if (n == (J)) { ka##M = ya; kb##M = yb; }                            \
        aw[(S) % 5] = ya; bw[(S) % 5] = yb;                                  \
    }

#define STORE(M) sp[8 * (M)] = make_float2(ka##M, kb##M);

    // 25 superblocks x 40 steps: t = 5 .. 1004
    for (int sb = 0; sb < 25; ++sb) {
        float ka0 = 0, kb0 = 0, ka1 = 0, kb1 = 0, ka2 = 0, kb2 = 0,
              ka3 = 0, kb3 = 0, ka4 = 0, kb4 = 0;
        // gg0: compute A (g0), load B (g1)
        LOADN(unB)
        STEP(0, unA, 0, 0) STEP(1, unA, 1, 0) STEP(2, unA, 2, 0)
        STEP(3, unA, 3, 0) STEP(4, unA, 4, 0)
        // gg1: compute B, load A
        LOADN(unA)
        STEP(0, unB, 5, 0) STEP(1, unB, 6, 0) STEP(2, unB, 7, 0) STORE(0)
        STEP(3, unB, 0, 1) STEP(4, unB, 1, 1)
        // gg2
        LOADN(unB)
        STEP(0, unA, 2, 1) STEP(1, unA, 3, 1) STEP(2, unA, 4, 1)
        STEP(3, unA, 5, 1) STEP(4, unA, 6, 1)
        // gg3
        LOADN(unA)
        STEP(0, unB, 7, 1) STORE(1)
        STEP(1, unB, 0, 2) STEP(2, unB, 1, 2) STEP(3, unB, 2, 2) STEP(4, unB, 3, 2)
        // gg4
        LOADN(unB)
        STEP(0, unA, 4, 2) STEP(1, unA, 5, 2) STEP(2, unA, 6, 2)
        STEP(3, unA, 7, 2) STORE(2)
        STEP(4, unA, 0, 3)
        // gg5
        LOADN(unA)
        STEP(0, unB, 1, 3) STEP(1, unB, 2, 3) STEP(2, unB, 3, 3)
        STEP(3, unB, 4, 3) STEP(4, unB, 5, 3)
        // gg6
        LOADN(unB)
        STEP(0, unA, 6, 3) STEP(1, unA, 7, 3) STORE(3)
        STEP(2, unA, 0, 4) STEP(3, unA, 1, 4) STEP(4, unA, 2, 4)
        // gg7
        LOADN(unA)
        STEP(0, unB, 3, 4) STEP(1, unB, 4, 4) STEP(2, unB, 5, 4)
        STEP(3, unB, 6, 4) STEP(4, unB, 7, 4) STORE(4)

        sp += 40;
    }

    // ---- tail: t = 1005..1018 (14 steps), per-step lane-0 stores ----
    // unA currently holds group t0=1005; upn points at t0=1010
    float2* tp = outb + 1005;
#define TSTEP(S, UN, K)                                                      \
    {                                                                        \
        float z0 = w1row[0] * UN[S];                                         \
        float z1 = w1row[5] * aw[(S) % 5];                                   \
        float z2 = fmaf(w1row[10], bw[(S) % 5], b1r);                        \
        z0 = fmaf(w1row[1], UN[(S) + 1], z0);                                \
        z1 = fmaf(w1row[6], aw[((S) + 1) % 5], z1);                          \
        z2 = fmaf(w1row[11], bw[((S) + 1) % 5], z2);                         \
        z0 = fmaf(w1row[2], UN[(S) + 2], z0);                                \
        z1 = fmaf(w1row[7], aw[((S) + 2) % 5], z1);                          \
        z2 = fmaf(w1row[12], bw[((S) + 2) % 5], z2);                         \
        z0 = fmaf(w1row[3], UN[(S) + 3], z0);                                \
        z1 = fmaf(w1row[8], aw[((S) + 3) % 5], z1);                          \
        z2 = fmaf(w1row[13], bw[((S) + 3) % 5], z2);                         \
        z0 = fmaf(w1row[4], UN[(S) + 4], z0);                                \
        z1 = fmaf(w1row[9], aw[((S) + 4) % 5], z1);                          \
        z2 = fmaf(w1row[14], bw[((S) + 4) % 5], z2);                         \
        float z = (z0 + z1) + z2;                                            \
        float r = __builtin_amdgcn_rcpf(fast_exp2(z) + 1.0f);                \
        float ya = sum8(fmaf(c1a, r, c0a));                                  \
        float yb = sum8(fmaf(c1b, r, c0b));                                  \
        if (is_store_lane) tp[K] = make_float2(ya, yb);                      \
        aw[(S) % 5] = ya; bw[(S) % 5] = yb;                                  \
    }

    TSTEP(0, unA, 0) TSTEP(1, unA, 1) TSTEP(2, unA, 2) TSTEP(3, unA, 3) TSTEP(4, unA, 4)
    LOADN(unB)   // t0=1010, rows 1010..1018
    TSTEP(0, unB, 5) TSTEP(1, unB, 6) TSTEP(2, unB, 7) TSTEP(3, unB, 8) TSTEP(4, unB, 9)
    LOADN(unA)   // t0=1015, rows 1015..1023 (in bounds)
    TSTEP(0, unA, 10) TSTEP(1, unA, 11) TSTEP(2, unA, 12) TSTEP(3, unA, 13)

#undef TSTEP
#undef STORE
#undef STEP
#undef LOADN
}

extern "C" void kernel_launch(void* const* d_in, const int* in_sizes, int n_in,
                              void* d_out, int out_size, void* d_ws, size_t ws_size,
                              hipStream_t stream) {
    const float* traj = (const float*)d_in[0];
    const float* W1   = (const float*)d_in[1];
    const float* b1   = (const float*)d_in[2];
    const float* W2   = (const float*)d_in[3];
    const float* b2   = (const float*)d_in[4];
    float* out = (float*)d_out;

    // 8 lanes/element, 8 elements/wave -> 1024 single-wave blocks = 1 wave/SIMD chip-wide
    const int grid = 8192 / 8;
    MLP_or_nextstep_kernel<<<grid, 64, 0, stream>>>(traj, W1, b1, W2, b2, out);
}